// Round 6
// baseline (475.576 us; speedup 1.0000x reference)
//
#include <hip/hip_runtime.h>
#include <hip/hip_bf16.h>

#define B_  2
#define S_  2048
#define D_  2048
#define H_  16
#define DH_ 128
#define M_  (B_*S_)   // 4096

typedef __hip_bfloat16 bf16;
typedef float v4f __attribute__((ext_vector_type(4)));
typedef short v8s __attribute__((ext_vector_type(8)));

__device__ __forceinline__ short f2s(float x) {
  bf16 h = __float2bfloat16(x);
  return *reinterpret_cast<const short*>(&h);
}
// load 8 contiguous f32 elems, convert to bf16 bits
__device__ __forceinline__ v8s ld8(const float* p) {
  v4f a = *reinterpret_cast<const v4f*>(p);
  v4f b = *reinterpret_cast<const v4f*>(p + 4);
  v8s r = { f2s(a[0]), f2s(a[1]), f2s(a[2]), f2s(a[3]),
            f2s(b[0]), f2s(b[1]), f2s(b[2]), f2s(b[3]) };
  return r;
}
__device__ __forceinline__ void store_out(bf16* p, float v)  { *p = __float2bfloat16(v); }
__device__ __forceinline__ void store_out(float* p, float v) { *p = v; }

// async 16B global->LDS (direct, no VGPR round-trip). LDS dest is
// wave-uniform base + lane*16; global src is per-lane.
__device__ __forceinline__ void gll16(const bf16* g, bf16* l) {
  __builtin_amdgcn_global_load_lds((const __attribute__((address_space(1))) void*)g,
                                   (__attribute__((address_space(3))) void*)l,
                                   16, 0, 0);
}

// streaming f32 -> bf16 convert, 8 elems/thread
__global__ __launch_bounds__(256) void cvt_f32_bf16(const float* __restrict__ in,
                                                    bf16* __restrict__ out, int n8) {
  int i = blockIdx.x * 256 + threadIdx.x;
  if (i >= n8) return;
  *reinterpret_cast<v8s*>(out + (size_t)i * 8) = ld8(in + (size_t)i * 8);
}

// C = A @ W^T + bias ; A [M,K] bf16 row-major, W [N,K] bf16 row-major.
// 128x128 tile, BK=64, single-buffered LDS (32 KiB -> 2 blocks/CU TLP),
// global_load_lds width-16 staging with both-sides XOR swizzle (rule 21).
// Round-5 verified (~490 TF/unit at these shapes).
// MODE 0: QK fused, W=[Wq;Wk] (N=4096). n<2048 -> Q (scaled) else K.
// MODE 2: V -> [B,H,dh,S]  (transposed for PV fragment loads)
// MODE 3: plain [M,N] f32 out (final projection)
template <int MODE, typename TOUT>
__global__ __launch_bounds__(256) void gemm_bt(const bf16* __restrict__ A,
                                               const bf16* __restrict__ W,
                                               const float* __restrict__ bias0,
                                               const float* __restrict__ bias1,
                                               TOUT* __restrict__ out0,
                                               TOUT* __restrict__ out1) {
  __shared__ __align__(16) bf16 As[128 * 64];
  __shared__ __align__(16) bf16 Bs[128 * 64];
  const int tid  = threadIdx.x;
  const int lane = tid & 63, wave = tid >> 6;
  const int wm = wave >> 1, wn = wave & 1;
  const int quad = lane >> 4, l16 = lane & 15;
  const int swz  = l16 & 7;
  const int bm = blockIdx.y * 128, bn = blockIdx.x * 128;

  const bf16* Arow = A + (size_t)bm * D_;
  const bf16* Wrow = W + (size_t)bn * D_;

  v4f acc[4][4] = {};
  for (int k0 = 0; k0 < D_; k0 += 64) {
#pragma unroll
    for (int j = 0; j < 4; ++j) {
      const int blk = j * 256 + tid;
      const int row = blk >> 3, c = blk & 7;
      const int gcol = k0 + (((c ^ (row & 7)) << 3));
      gll16(Arow + (size_t)row * D_ + gcol, As + j * 2048 + wave * 512);
      gll16(Wrow + (size_t)row * D_ + gcol, Bs + j * 2048 + wave * 512);
    }
    __syncthreads();   // compiler drains vmcnt before s_barrier
    v8s af[4][2], bfr[4][2];
#pragma unroll
    for (int mi = 0; mi < 4; ++mi)
#pragma unroll
      for (int kk = 0; kk < 2; ++kk)
        af[mi][kk] = *reinterpret_cast<const v8s*>(
            &As[(wm * 64 + mi * 16 + l16) * 64 + (((kk * 4 + quad) ^ swz) << 3)]);
#pragma unroll
    for (int ni = 0; ni < 4; ++ni)
#pragma unroll
      for (int kk = 0; kk < 2; ++kk)
        bfr[ni][kk] = *reinterpret_cast<const v8s*>(
            &Bs[(wn * 64 + ni * 16 + l16) * 64 + (((kk * 4 + quad) ^ swz) << 3)]);
#pragma unroll
    for (int kk = 0; kk < 2; ++kk)
#pragma unroll
      for (int mi = 0; mi < 4; ++mi)
#pragma unroll
        for (int ni = 0; ni < 4; ++ni)
          acc[mi][ni] = __builtin_amdgcn_mfma_f32_16x16x32_bf16(
              af[mi][kk], bfr[ni][kk], acc[mi][ni], 0, 0, 0);
    __syncthreads();
  }

  constexpr float QSCALE = 0.12752003912f;  // 1/sqrt(128) * log2(e)
  const int proj = (MODE == 0) ? (bn >> 11) : 0;   // block-uniform: 0=Q, 1=K
  const float* bias = proj ? bias1 : bias0;
  TOUT* outp = proj ? out1 : out0;
  const int bnl = bn & 2047;
#pragma unroll
  for (int ni = 0; ni < 4; ++ni) {
    const int nl = bnl + wn * 64 + ni * 16 + l16;   // 0..2047 within projection
    const float bv = bias[nl];
#pragma unroll
    for (int mi = 0; mi < 4; ++mi) {
      const int m0 = bm + wm * 64 + mi * 16 + quad * 4;
#pragma unroll
      for (int r = 0; r < 4; ++r) {
        const int m = m0 + r;           // row m: (b,s). col nl: (h,d)
        float v = acc[mi][ni][r] + bv;
        size_t idx;
        if (MODE == 0) {
          if (!proj) v *= QSCALE;
          int b = m >> 11, s = m & (S_ - 1);
          int h = nl >> 7, d = nl & (DH_ - 1);
          idx = ((size_t)(b * H_ + h) * S_ + s) * DH_ + d;
        } else if (MODE == 2) {
          int b = m >> 11, s = m & (S_ - 1);
          int h = nl >> 7, d = nl & (DH_ - 1);
          idx = ((size_t)(b * H_ + h) * DH_ + d) * S_ + s;
        } else {
          idx = (size_t)m * D_ + nl;
        }
        store_out(outp + idx, v);
      }
    }
  }
}

// Flash attention, causal. Q/K: [B,H,S,dh], Vt: [B,H,dh,S] (all bf16). Out: [B,S,D] bf16.
// Block = 128 Q rows (8 waves x 16 rows), K-tile = 64 keys, 512 threads.
// DOUBLE-BUFFERED K/V via global_load_lds (XOR-swizzled global source, same
// XOR on reads). No separate P LDS: after barrier #1 (all QK^T done) the
// current K buffer is dead and each wave uses its 2 KB slice of it as P
// scratch (XOR-swizzled -> 2-way banks only). LDS = 64 KB -> 2 blocks/CU.
// Per tile: prefetch(kt+1)->buf[1-c] | QK(buf c) | barrier | P->Ks[c],
// lgkmcnt, PV(Vs[c]) | vmcnt(0)+barrier | swap.  Stage latency hidden
// under the whole iter body instead of serial drain.
#define QBLK 128
__global__ __launch_bounds__(512, 4) void attn_fused(const bf16* __restrict__ Q,
                                                     const bf16* __restrict__ K,
                                                     const bf16* __restrict__ Vt,
                                                     bf16* __restrict__ Oa) {
  __shared__ __align__(16) bf16 Ks[2][64 * 128];  // [key][d] linear; blk c holds global c^(key&7)
  __shared__ __align__(16) bf16 Vs[2][128 * 64];  // [d][key] linear; blk c holds global c^(d&7)
  const int tid  = threadIdx.x;
  const int lane = tid & 63, wave = tid >> 6;
  const int quad = lane >> 4, l16 = lane & 15;
  const int swz  = l16 & 7;
  // longest-first: work per block ~ qt, launch big blocks first.
  const int qt = (int)gridDim.x - 1 - (int)blockIdx.x;
  const int bh = blockIdx.y;
  const int b = bh >> 4, h = bh & 15;
  const bf16* Qh = Q  + (size_t)bh * S_ * DH_;
  const bf16* Kh = K  + (size_t)bh * S_ * DH_;
  const bf16* Vh = Vt + (size_t)bh * DH_ * S_;

  const int qrow0 = qt * QBLK + wave * 16;
  v8s qf[4];
#pragma unroll
  for (int kk = 0; kk < 4; ++kk)
    qf[kk] = *reinterpret_cast<const v8s*>(&Qh[(size_t)(qrow0 + l16) * DH_ + kk * 32 + quad * 8]);

  v4f acc_o[8] = {};
  float m_i[4], l_i[4];
#pragma unroll
  for (int r = 0; r < 4; ++r) { m_i[r] = -1.0e30f; l_i[r] = 0.f; }

  const int nkt = 2 * qt + 2;

  // prologue: stage tile 0 into buf 0
#pragma unroll
  for (int rr = 0; rr < 2; ++rr) {
    const int g = rr * 512 + tid;
    const int krow = g >> 4, kc = g & 15;           // K: 16 x 16B blocks/row
    gll16(Kh + (size_t)krow * DH_ + ((kc ^ (krow & 7)) << 3),
          &Ks[0][(rr * 512 + wave * 64) * 8]);
    const int vrow = g >> 3, vc = g & 7;            // V: 8 x 16B blocks/row
    gll16(Vh + (size_t)vrow * S_ + ((vc ^ (vrow & 7)) << 3),
          &Vs[0][(rr * 512 + wave * 64) * 8]);
  }
  asm volatile("s_waitcnt vmcnt(0)" ::: "memory");
  __syncthreads();

  for (int kt = 0; kt < nkt; ++kt) {
    const int kbase = kt * 64;
    const int c = kt & 1;
    // issue next-tile prefetch into the other buffer (hidden under this iter)
    if (kt + 1 < nkt) {
      const int nbase = kbase + 64;
#pragma unroll
      for (int rr = 0; rr < 2; ++rr) {
        const int g = rr * 512 + tid;
        const int krow = g >> 4, kc = g & 15;
        gll16(Kh + (size_t)(nbase + krow) * DH_ + ((kc ^ (krow & 7)) << 3),
              &Ks[c ^ 1][(rr * 512 + wave * 64) * 8]);
        const int vrow = g >> 3, vc = g & 7;
        gll16(Vh + (size_t)vrow * S_ + nbase + ((vc ^ (vrow & 7)) << 3),
              &Vs[c ^ 1][(rr * 512 + wave * 64) * 8]);
      }
    }

    const bool active = (kbase <= qrow0 + 15);
    v4f sc[4];
    if (active) {
      // S = Q K^T (Q pre-scaled by 1/sqrt(dh)*log2e)
      __builtin_amdgcn_s_setprio(1);
#pragma unroll
      for (int nt = 0; nt < 4; ++nt) {
        v4f a = {};
#pragma unroll
        for (int kk = 0; kk < 4; ++kk) {
          v8s kf = *reinterpret_cast<const v8s*>(
              &Ks[c][(nt * 16 + l16) * 128 + (((kk * 4 + quad) ^ swz) << 3)]);
          a = __builtin_amdgcn_mfma_f32_16x16x32_bf16(qf[kk], kf, a, 0, 0, 0);
        }
        sc[nt] = a;
      }
      __builtin_amdgcn_s_setprio(0);
      if (kbase + 63 > qrow0) {   // diagonal tile: causal mask
#pragma unroll
        for (int nt = 0; nt < 4; ++nt)
#pragma unroll
          for (int r = 0; r < 4; ++r) {
            int kc2 = kbase + nt * 16 + l16;
            int qr = qrow0 + quad * 4 + r;
            if (kc2 > qr) sc[nt][r] = -1.0e30f;
          }
      }
    }
    // all waves: QK^T of Ks[c] complete -> Ks[c] reusable as P scratch
    __syncthreads();

    if (active) {
      // online softmax; C-layout: row = quad*4 + r, col = nt*16 + l16
#pragma unroll
      for (int r = 0; r < 4; ++r) {
        float mx = fmaxf(fmaxf(sc[0][r], sc[1][r]), fmaxf(sc[2][r], sc[3][r]));
        mx = fmaxf(mx, __shfl_xor(mx, 1));
        mx = fmaxf(mx, __shfl_xor(mx, 2));
        mx = fmaxf(mx, __shfl_xor(mx, 4));
        mx = fmaxf(mx, __shfl_xor(mx, 8));
        // T13 defer-max: only rescale when max grew by >8 (log2 domain)
        if (mx > m_i[r] + 8.0f) {
          float alpha = exp2f(m_i[r] - mx);
          m_i[r] = mx;
          l_i[r] *= alpha;
#pragma unroll
          for (int nt8 = 0; nt8 < 8; ++nt8) acc_o[nt8][r] *= alpha;
        }
        const float mm = m_i[r];
        float s0 = exp2f(sc[0][r] - mm);
        float s1 = exp2f(sc[1][r] - mm);
        float s2 = exp2f(sc[2][r] - mm);
        float s3 = exp2f(sc[3][r] - mm);
        sc[0][r] = s0; sc[1][r] = s1; sc[2][r] = s2; sc[3][r] = s3;
        float t = s0 + s1 + s2 + s3;
        t += __shfl_xor(t, 1); t += __shfl_xor(t, 2);
        t += __shfl_xor(t, 4); t += __shfl_xor(t, 8);
        l_i[r] += t;
      }
      // P: C-layout regs -> per-wave 2KB slice of dead Ks[c], XOR-swizzled
      // (16B block ^= row&7 -> pf read is 2-way-bank only)
      bf16* Pw = &Ks[c][wave * 1024];
#pragma unroll
      for (int nt = 0; nt < 4; ++nt)
#pragma unroll
        for (int r = 0; r < 4; ++r) {
          const int row = quad * 4 + r, col = nt * 16 + l16;
          Pw[row * 64 + ((((col >> 3) ^ (row & 7)) << 3) | (col & 7))] =
              __float2bfloat16(sc[nt][r]);
        }
      // own-wave write->read ordering only; no cross-wave dep -> no barrier
      asm volatile("s_waitcnt lgkmcnt(0)" ::: "memory");
      // O += P V
      __builtin_amdgcn_s_setprio(1);
#pragma unroll
      for (int kk2 = 0; kk2 < 2; ++kk2) {
        v8s pf = *reinterpret_cast<const v8s*>(
            &Pw[l16 * 64 + (((kk2 * 4 + quad) ^ swz) << 3)]);
#pragma unroll
        for (int nt8 = 0; nt8 < 8; ++nt8) {
          v8s vf = *reinterpret_cast<const v8s*>(
              &Vs[c][(nt8 * 16 + l16) * 64 + (((kk2 * 4 + quad) ^ swz) << 3)]);
          acc_o[nt8] = __builtin_amdgcn_mfma_f32_16x16x32_bf16(pf, vf, acc_o[nt8], 0, 0, 0);
        }
      }
      __builtin_amdgcn_s_setprio(0);
    }
    // prefetch landed (per-wave) + PV/P-scratch of buf c done everywhere
    asm volatile("s_waitcnt vmcnt(0)" ::: "memory");
    __syncthreads();
  }

#pragma unroll
  for (int r = 0; r < 4; ++r) {
    const float inv = 1.0f / l_i[r];
    const int srow = qrow0 + quad * 4 + r;
#pragma unroll
    for (int nt8 = 0; nt8 < 8; ++nt8)
      Oa[((size_t)b * S_ + srow) * D_ + h * DH_ + nt8 * 16 + l16] =
          __float2bfloat16(acc_o[nt8][r] * inv);
  }
}

extern "C" void kernel_launch(void* const* d_in, const int* in_sizes, int n_in,
                              void* d_out, int out_size, void* d_ws, size_t ws_size,
                              hipStream_t stream) {
  // Canary: all-zero output (absmax exactly 3.5625) signals a tripped assumption.
  if (n_in != 9 ||
      in_sizes[0] != M_ * D_ ||
      in_sizes[1] != D_ * D_ || in_sizes[2] != D_ ||
      in_sizes[3] != D_ * D_ || in_sizes[4] != D_ ||
      in_sizes[5] != D_ * D_ || in_sizes[6] != D_ ||
      in_sizes[7] != D_ * D_ || in_sizes[8] != D_ ||
      out_size != M_ * D_)
    return;

  const float* x  = (const float*)d_in[0];
  const float* Wq = (const float*)d_in[1];
  const float* bq = (const float*)d_in[2];
  const float* Wk = (const float*)d_in[3];
  const float* bk = (const float*)d_in[4];
  const float* Wv = (const float*)d_in[5];
  const float* bv = (const float*)d_in[6];
  const float* Wo = (const float*)d_in[7];
  const float* bo = (const float*)d_in[8];
  float* out = (float*)d_out;   // OUTPUT IS FLOAT32 (reference output dtype)

  const size_t NT = (size_t)M_ * D_;   // 8388608 elems per tensor
  const size_t WN = (size_t)D_ * D_;   // 4194304 elems per weight
  // Buffer plan:
  //   d_out (33.6 MB f32):  [0,16.8) qws (bf16 Q), [16.8,33.6) x_bf16
  //     both dead before the final GEMM overwrites d_out.
  //   ws (50.3 MB): kws | vtw | aws
  //     Wq||Wk concat (16.8 MB) fills aws before the QK GEMM; Wv reuses
  //     aws[0:8.4) before the V GEMM; aws becomes the attn output after
  //     (weights dead); Wo parks in kws (K dead after attn).
  bf16* qws   = (bf16*)d_out;
  bf16* xbf   = (bf16*)d_out + NT;
  bf16* kws   = (bf16*)d_ws;
  bf16* vtw   = kws + NT;
  bf16* aws   = vtw + NT;
  bf16* wqk   = aws;            // [4096][2048] bf16 concat
  bf16* wv_s  = aws;            // [2048][2048]
  bf16* wo_s  = kws;            // [2048][2048] (post-attn)

  const int N8X = M_ * D_ / 8;   // 1048576
  const int N8W = D_ * D_ / 8;   // 524288

  dim3 bb(256);
  cvt_f32_bf16<<<N8X / 256, bb, 0, stream>>>(x, xbf, N8X);
  cvt_f32_bf16<<<N8W / 256, bb, 0, stream>>>(Wq, wqk, N8W);
  cvt_f32_bf16<<<N8W / 256, bb, 0, stream>>>(Wk, wqk + WN, N8W);

  // QK fused: N=4096, grid 32x32 = 1024 blocks
  gemm_bt<0, bf16><<<dim3(32, 32), bb, 0, stream>>>(xbf, wqk, bq, bk, qws, kws);

  cvt_f32_bf16<<<N8W / 256, bb, 0, stream>>>(Wv, wv_s, N8W);
  gemm_bt<2, bf16><<<dim3(16, 32), bb, 0, stream>>>(xbf, wv_s, bv, bv, vtw, vtw);

  attn_fused<<<dim3(S_ / QBLK, B_ * H_), dim3(512), 0, stream>>>(qws, kws, vtw, aws);

  cvt_f32_bf16<<<N8W / 256, bb, 0, stream>>>(Wo, wo_s, N8W);
  gemm_bt<3, float><<<dim3(16, 32), bb, 0, stream>>>(aws, wo_s, bo, bo, out, out);
}

// Round 7
// 412.488 us; speedup vs baseline: 1.1529x; 1.1529x over previous
//
#include <hip/hip_runtime.h>
#include <hip/hip_bf16.h>

#define B_  2
#define S_  2048
#define D_  2048
#define H_  16
#define DH_ 128
#define M_  (B_*S_)   // 4096

typedef __hip_bfloat16 bf16;
typedef float v4f __attribute__((ext_vector_type(4)));
typedef short v8s __attribute__((ext_vector_type(8)));

__device__ __forceinline__ short f2s(float x) {
  bf16 h = __float2bfloat16(x);
  return *reinterpret_cast<const short*>(&h);
}
// load 8 contiguous f32 elems, convert to bf16 bits
__device__ __forceinline__ v8s ld8(const float* p) {
  v4f a = *reinterpret_cast<const v4f*>(p);
  v4f b = *reinterpret_cast<const v4f*>(p + 4);
  v8s r = { f2s(a[0]), f2s(a[1]), f2s(a[2]), f2s(a[3]),
            f2s(b[0]), f2s(b[1]), f2s(b[2]), f2s(b[3]) };
  return r;
}
__device__ __forceinline__ void store_out(bf16* p, float v)  { *p = __float2bfloat16(v); }
__device__ __forceinline__ void store_out(float* p, float v) { *p = v; }

// async 16B global->LDS (direct, no VGPR round-trip). LDS dest is
// wave-uniform base + lane*16; global src is per-lane.
__device__ __forceinline__ void gll16(const bf16* g, bf16* l) {
  __builtin_amdgcn_global_load_lds((const __attribute__((address_space(1))) void*)g,
                                   (__attribute__((address_space(3))) void*)l,
                                   16, 0, 0);
}

// streaming f32 -> bf16 convert, 8 elems/thread
__global__ __launch_bounds__(256) void cvt_f32_bf16(const float* __restrict__ in,
                                                    bf16* __restrict__ out, int n8) {
  int i = blockIdx.x * 256 + threadIdx.x;
  if (i >= n8) return;
  *reinterpret_cast<v8s*>(out + (size_t)i * 8) = ld8(in + (size_t)i * 8);
}

// merged convert: x (4096 blocks) + Wq (2048) + Wk (2048) in one launch
__global__ __launch_bounds__(256) void cvt3_f32_bf16(const float* __restrict__ a, bf16* __restrict__ oa,
                                                     const float* __restrict__ b, bf16* __restrict__ ob,
                                                     const float* __restrict__ c, bf16* __restrict__ oc) {
  const int bx = blockIdx.x;
  if (bx < 4096) {
    size_t i = (size_t)bx * 256 + threadIdx.x;
    *reinterpret_cast<v8s*>(oa + i * 8) = ld8(a + i * 8);
  } else if (bx < 6144) {
    size_t i = (size_t)(bx - 4096) * 256 + threadIdx.x;
    *reinterpret_cast<v8s*>(ob + i * 8) = ld8(b + i * 8);
  } else {
    size_t i = (size_t)(bx - 6144) * 256 + threadIdx.x;
    *reinterpret_cast<v8s*>(oc + i * 8) = ld8(c + i * 8);
  }
}

// C = A @ W^T + bias ; A [M,K] bf16 row-major, W [N,K] bf16 row-major.
// 128x128 tile, BK=64, single-buffered LDS (32 KiB), global_load_lds
// width-16 staging with both-sides XOR swizzle (rule 21).
// Round-5 verified (~490 TF/unit at these shapes).
// MODE 0: QK fused, W=[Wq;Wk] (N=4096). n<2048 -> Q (scaled) else K.
// MODE 2: V -> [B,H,dh,S]  (transposed for PV fragment loads)
// MODE 3: plain [M,N] f32 out (final projection)
template <int MODE, typename TOUT>
__global__ __launch_bounds__(256) void gemm_bt(const bf16* __restrict__ A,
                                               const bf16* __restrict__ W,
                                               const float* __restrict__ bias0,
                                               const float* __restrict__ bias1,
                                               TOUT* __restrict__ out0,
                                               TOUT* __restrict__ out1) {
  __shared__ __align__(16) bf16 As[128 * 64];
  __shared__ __align__(16) bf16 Bs[128 * 64];
  const int tid  = threadIdx.x;
  const int lane = tid & 63, wave = tid >> 6;
  const int wm = wave >> 1, wn = wave & 1;
  const int quad = lane >> 4, l16 = lane & 15;
  const int swz  = l16 & 7;
  const int bm = blockIdx.y * 128, bn = blockIdx.x * 128;

  const bf16* Arow = A + (size_t)bm * D_;
  const bf16* Wrow = W + (size_t)bn * D_;

  v4f acc[4][4] = {};
  for (int k0 = 0; k0 < D_; k0 += 64) {
#pragma unroll
    for (int j = 0; j < 4; ++j) {
      const int blk = j * 256 + tid;
      const int row = blk >> 3, c = blk & 7;
      const int gcol = k0 + (((c ^ (row & 7)) << 3));
      gll16(Arow + (size_t)row * D_ + gcol, As + j * 2048 + wave * 512);
      gll16(Wrow + (size_t)row * D_ + gcol, Bs + j * 2048 + wave * 512);
    }
    __syncthreads();   // compiler drains vmcnt before s_barrier
    v8s af[4][2], bfr[4][2];
#pragma unroll
    for (int mi = 0; mi < 4; ++mi)
#pragma unroll
      for (int kk = 0; kk < 2; ++kk)
        af[mi][kk] = *reinterpret_cast<const v8s*>(
            &As[(wm * 64 + mi * 16 + l16) * 64 + (((kk * 4 + quad) ^ swz) << 3)]);
#pragma unroll
    for (int ni = 0; ni < 4; ++ni)
#pragma unroll
      for (int kk = 0; kk < 2; ++kk)
        bfr[ni][kk] = *reinterpret_cast<const v8s*>(
            &Bs[(wn * 64 + ni * 16 + l16) * 64 + (((kk * 4 + quad) ^ swz) << 3)]);
#pragma unroll
    for (int kk = 0; kk < 2; ++kk)
#pragma unroll
      for (int mi = 0; mi < 4; ++mi)
#pragma unroll
        for (int ni = 0; ni < 4; ++ni)
          acc[mi][ni] = __builtin_amdgcn_mfma_f32_16x16x32_bf16(
              af[mi][kk], bfr[ni][kk], acc[mi][ni], 0, 0, 0);
    __syncthreads();
  }

  constexpr float QSCALE = 0.12752003912f;  // 1/sqrt(128) * log2(e)
  const int proj = (MODE == 0) ? (bn >> 11) : 0;   // block-uniform: 0=Q, 1=K
  const float* bias = proj ? bias1 : bias0;
  TOUT* outp = proj ? out1 : out0;
  const int bnl = bn & 2047;
#pragma unroll
  for (int ni = 0; ni < 4; ++ni) {
    const int nl = bnl + wn * 64 + ni * 16 + l16;   // 0..2047 within projection
    const float bv = bias[nl];
#pragma unroll
    for (int mi = 0; mi < 4; ++mi) {
      const int m0 = bm + wm * 64 + mi * 16 + quad * 4;
#pragma unroll
      for (int r = 0; r < 4; ++r) {
        const int m = m0 + r;           // row m: (b,s). col nl: (h,d)
        float v = acc[mi][ni][r] + bv;
        size_t idx;
        if (MODE == 0) {
          if (!proj) v *= QSCALE;
          int b = m >> 11, s = m & (S_ - 1);
          int h = nl >> 7, d = nl & (DH_ - 1);
          idx = ((size_t)(b * H_ + h) * S_ + s) * DH_ + d;
        } else if (MODE == 2) {
          int b = m >> 11, s = m & (S_ - 1);
          int h = nl >> 7, d = nl & (DH_ - 1);
          idx = ((size_t)(b * H_ + h) * DH_ + d) * S_ + s;
        } else {
          idx = (size_t)m * D_ + nl;
        }
        store_out(outp + idx, v);
      }
    }
  }
}

// Flash attention, causal. Q/K: [B,H,S,dh], Vt: [B,H,dh,S] (all bf16). Out: [B,S,D] bf16.
// Block = 128 Q rows (8 waves x 16 rows), K-tile = 64 keys, 512 threads.
// Round-5 verified configuration (146 us; 50 KB LDS -> 3 blocks/CU TLP, the
// proven occupancy sweet spot): single-buffered K/V staged via global_load_lds
// with XOR-swizzled GLOBAL source; reads apply the same XOR.
// qt mapping: y<16 descending in x, y>=16 ascending -> under round-robin
// block->CU placement (bids c and c+256 on one CU) each CU's pair of blocks
// sums to ~constant work; bijective per (bh,qt) either way.
#define QBLK 128
__global__ __launch_bounds__(512, 4) void attn_fused(const bf16* __restrict__ Q,
                                                     const bf16* __restrict__ K,
                                                     const bf16* __restrict__ Vt,
                                                     bf16* __restrict__ Oa) {
  __shared__ __align__(16) bf16 Ks[64 * 128];   // [key][d] linear; blk c holds global c^(key&7)
  __shared__ __align__(16) bf16 Vs[128 * 64];   // [d][key] linear; blk c holds global c^(d&7)
  __shared__ __align__(16) bf16 Ps[8][16 * 72]; // per-wave P, padded stride 72
  const int tid  = threadIdx.x;
  const int lane = tid & 63, wave = tid >> 6;
  const int quad = lane >> 4, l16 = lane & 15;
  const int swz  = l16 & 7;
  const int qtd = (int)gridDim.x - 1 - (int)blockIdx.x;   // descending
  const int qt  = (blockIdx.y & 16) ? (int)blockIdx.x : qtd;
  const int bh = blockIdx.y;
  const int b = bh >> 4, h = bh & 15;
  const bf16* Qh = Q  + (size_t)bh * S_ * DH_;
  const bf16* Kh = K  + (size_t)bh * S_ * DH_;
  const bf16* Vh = Vt + (size_t)bh * DH_ * S_;

  const int qrow0 = qt * QBLK + wave * 16;
  v8s qf[4];
#pragma unroll
  for (int kk = 0; kk < 4; ++kk)
    qf[kk] = *reinterpret_cast<const v8s*>(&Qh[(size_t)(qrow0 + l16) * DH_ + kk * 32 + quad * 8]);

  v4f acc_o[8] = {};
  float m_i[4], l_i[4];
#pragma unroll
  for (int r = 0; r < 4; ++r) { m_i[r] = -1.0e30f; l_i[r] = 0.f; }

  const int nkt = 2 * qt + 2;
  for (int kt = 0; kt < nkt; ++kt) {
    const int kbase = kt * 64;
    // --- stage K (64x256B) and V (128x128B) via global_load_lds, 2 rounds ---
#pragma unroll
    for (int rr = 0; rr < 2; ++rr) {
      const int g = rr * 512 + tid;
      const int krow = g >> 4, kc = g & 15;           // K: 16 x 16B blocks/row
      gll16(Kh + (size_t)(kbase + krow) * DH_ + ((kc ^ (krow & 7)) << 3),
            Ks + rr * 4096 + wave * 512);
      const int vrow = g >> 3, vc = g & 7;            // V: 8 x 16B blocks/row
      gll16(Vh + (size_t)vrow * S_ + kbase + ((vc ^ (vrow & 7)) << 3),
            Vs + rr * 4096 + wave * 512);
    }
    __syncthreads();   // drains vmcnt (gll16) + all waves staged

    const bool active = (kbase <= qrow0 + 15);
    if (active) {
      // S = Q K^T (Q pre-scaled by 1/sqrt(dh)*log2e)
      v4f sc[4];
      __builtin_amdgcn_s_setprio(1);
#pragma unroll
      for (int nt = 0; nt < 4; ++nt) {
        v4f a = {};
#pragma unroll
        for (int kk = 0; kk < 4; ++kk) {
          v8s kf = *reinterpret_cast<const v8s*>(
              &Ks[(nt * 16 + l16) * 128 + (((kk * 4 + quad) ^ swz) << 3)]);
          a = __builtin_amdgcn_mfma_f32_16x16x32_bf16(qf[kk], kf, a, 0, 0, 0);
        }
        sc[nt] = a;
      }
      __builtin_amdgcn_s_setprio(0);
      if (kbase + 63 > qrow0) {   // diagonal tile: causal mask
#pragma unroll
        for (int nt = 0; nt < 4; ++nt)
#pragma unroll
          for (int r = 0; r < 4; ++r) {
            int kc2 = kbase + nt * 16 + l16;
            int qr = qrow0 + quad * 4 + r;
            if (kc2 > qr) sc[nt][r] = -1.0e30f;
          }
      }
      // online softmax; C-layout: row = quad*4 + r, col = nt*16 + l16
#pragma unroll
      for (int r = 0; r < 4; ++r) {
        float mx = fmaxf(fmaxf(sc[0][r], sc[1][r]), fmaxf(sc[2][r], sc[3][r]));
        mx = fmaxf(mx, __shfl_xor(mx, 1));
        mx = fmaxf(mx, __shfl_xor(mx, 2));
        mx = fmaxf(mx, __shfl_xor(mx, 4));
        mx = fmaxf(mx, __shfl_xor(mx, 8));
        // T13 defer-max: only rescale when max grew by >8 (log2 domain)
        if (mx > m_i[r] + 8.0f) {
          float alpha = exp2f(m_i[r] - mx);
          m_i[r] = mx;
          l_i[r] *= alpha;
#pragma unroll
          for (int nt8 = 0; nt8 < 8; ++nt8) acc_o[nt8][r] *= alpha;
        }
        const float mm = m_i[r];
        float s0 = exp2f(sc[0][r] - mm);
        float s1 = exp2f(sc[1][r] - mm);
        float s2 = exp2f(sc[2][r] - mm);
        float s3 = exp2f(sc[3][r] - mm);
        sc[0][r] = s0; sc[1][r] = s1; sc[2][r] = s2; sc[3][r] = s3;
        float t = s0 + s1 + s2 + s3;
        t += __shfl_xor(t, 1); t += __shfl_xor(t, 2);
        t += __shfl_xor(t, 4); t += __shfl_xor(t, 8);
        l_i[r] += t;
      }
      // P: C-layout regs -> per-wave LDS (bf16) -> A-layout frags
#pragma unroll
      for (int nt = 0; nt < 4; ++nt)
#pragma unroll
        for (int r = 0; r < 4; ++r)
          Ps[wave][(quad * 4 + r) * 72 + nt * 16 + l16] = __float2bfloat16(sc[nt][r]);
      // own-wave write->read ordering only; no cross-wave dep -> no barrier
      asm volatile("s_waitcnt lgkmcnt(0)" ::: "memory");
      // O += P V
      __builtin_amdgcn_s_setprio(1);
#pragma unroll
      for (int kk2 = 0; kk2 < 2; ++kk2) {
        v8s pf = *reinterpret_cast<const v8s*>(&Ps[wave][l16 * 72 + kk2 * 32 + quad * 8]);
#pragma unroll
        for (int nt8 = 0; nt8 < 8; ++nt8) {
          v8s vf = *reinterpret_cast<const v8s*>(
              &Vs[(nt8 * 16 + l16) * 64 + (((kk2 * 4 + quad) ^ swz) << 3)]);
          acc_o[nt8] = __builtin_amdgcn_mfma_f32_16x16x32_bf16(pf, vf, acc_o[nt8], 0, 0, 0);
        }
      }
      __builtin_amdgcn_s_setprio(0);
    }
    __syncthreads();   // Ks/Vs consumed; safe to restage
  }

#pragma unroll
  for (int r = 0; r < 4; ++r) {
    const float inv = 1.0f / l_i[r];
    const int srow = qrow0 + quad * 4 + r;
#pragma unroll
    for (int nt8 = 0; nt8 < 8; ++nt8)
      Oa[((size_t)b * S_ + srow) * D_ + h * DH_ + nt8 * 16 + l16] =
          __float2bfloat16(acc_o[nt8][r] * inv);
  }
}

extern "C" void kernel_launch(void* const* d_in, const int* in_sizes, int n_in,
                              void* d_out, int out_size, void* d_ws, size_t ws_size,
                              hipStream_t stream) {
  // Canary: all-zero output (absmax exactly 3.5625) signals a tripped assumption.
  if (n_in != 9 ||
      in_sizes[0] != M_ * D_ ||
      in_sizes[1] != D_ * D_ || in_sizes[2] != D_ ||
      in_sizes[3] != D_ * D_ || in_sizes[4] != D_ ||
      in_sizes[5] != D_ * D_ || in_sizes[6] != D_ ||
      in_sizes[7] != D_ * D_ || in_sizes[8] != D_ ||
      out_size != M_ * D_)
    return;

  const float* x  = (const float*)d_in[0];
  const float* Wq = (const float*)d_in[1];
  const float* bq = (const float*)d_in[2];
  const float* Wk = (const float*)d_in[3];
  const float* bk = (const float*)d_in[4];
  const float* Wv = (const float*)d_in[5];
  const float* bv = (const float*)d_in[6];
  const float* Wo = (const float*)d_in[7];
  const float* bo = (const float*)d_in[8];
  float* out = (float*)d_out;   // OUTPUT IS FLOAT32 (reference output dtype)

  const size_t NT = (size_t)M_ * D_;   // 8388608 elems per tensor
  const size_t WN = (size_t)D_ * D_;   // 4194304 elems per weight
  // Buffer plan:
  //   d_out (33.6 MB f32):  [0,16.8) qws (bf16 Q), [16.8,33.6) x_bf16
  //     both dead before the final GEMM overwrites d_out.
  //   ws (50.3 MB): kws | vtw | aws
  //     Wq||Wk concat (16.8 MB) fills aws before the QK GEMM; Wv reuses
  //     aws[0:8.4) before the V GEMM (aws slot is only free AFTER QK GEMM
  //     reads wqk); aws becomes the attn output after (weights dead);
  //     Wo parks in kws (K dead after attn).
  bf16* qws   = (bf16*)d_out;
  bf16* xbf   = (bf16*)d_out + NT;
  bf16* kws   = (bf16*)d_ws;
  bf16* vtw   = kws + NT;
  bf16* aws   = vtw + NT;
  bf16* wqk   = aws;            // [4096][2048] bf16 concat
  bf16* wv_s  = aws;            // [2048][2048]
  bf16* wo_s  = kws;            // [2048][2048] (post-attn)

  const int N8W = D_ * D_ / 8;   // 524288

  dim3 bb(256);
  // x + Wq + Wk in one merged convert launch (4096 + 2048 + 2048 blocks)
  cvt3_f32_bf16<<<8192, bb, 0, stream>>>(x, xbf, Wq, wqk, Wk, wqk + WN);

  // QK fused: N=4096, grid 32x32 = 1024 blocks
  gemm_bt<0, bf16><<<dim3(32, 32), bb, 0, stream>>>(xbf, wqk, bq, bk, qws, kws);

  cvt_f32_bf16<<<N8W / 256, bb, 0, stream>>>(Wv, wv_s, N8W);
  gemm_bt<2, bf16><<<dim3(16, 32), bb, 0, stream>>>(xbf, wv_s, bv, bv, vtw, vtw);

  attn_fused<<<dim3(S_ / QBLK, B_ * H_), dim3(512), 0, stream>>>(qws, kws, vtw, aws);

  cvt_f32_bf16<<<N8W / 256, bb, 0, stream>>>(Wo, wo_s, N8W);
  gemm_bt<3, float><<<dim3(16, 32), bb, 0, stream>>>(aws, wo_s, bo, bo, out, out);
}

// Round 8
// 407.097 us; speedup vs baseline: 1.1682x; 1.0132x over previous
//
#include <hip/hip_runtime.h>
#include <hip/hip_bf16.h>

#define B_  2
#define S_  2048
#define D_  2048
#define H_  16
#define DH_ 128
#define M_  (B_*S_)   // 4096

typedef __hip_bfloat16 bf16;
typedef float v4f __attribute__((ext_vector_type(4)));
typedef short v8s __attribute__((ext_vector_type(8)));

__device__ __forceinline__ short f2s(float x) {
  bf16 h = __float2bfloat16(x);
  return *reinterpret_cast<const short*>(&h);
}
// load 8 contiguous f32 elems, convert to bf16 bits
__device__ __forceinline__ v8s ld8(const float* p) {
  v4f a = *reinterpret_cast<const v4f*>(p);
  v4f b = *reinterpret_cast<const v4f*>(p + 4);
  v8s r = { f2s(a[0]), f2s(a[1]), f2s(a[2]), f2s(a[3]),
            f2s(b[0]), f2s(b[1]), f2s(b[2]), f2s(b[3]) };
  return r;
}
__device__ __forceinline__ void store_out(bf16* p, float v)  { *p = __float2bfloat16(v); }
__device__ __forceinline__ void store_out(float* p, float v) { *p = v; }

// async 16B global->LDS (direct, no VGPR round-trip). LDS dest is
// wave-uniform base + lane*16; global src is per-lane.
__device__ __forceinline__ void gll16(const bf16* g, bf16* l) {
  __builtin_amdgcn_global_load_lds((const __attribute__((address_space(1))) void*)g,
                                   (__attribute__((address_space(3))) void*)l,
                                   16, 0, 0);
}

// streaming f32 -> bf16 convert, 8 elems/thread
__global__ __launch_bounds__(256) void cvt_f32_bf16(const float* __restrict__ in,
                                                    bf16* __restrict__ out, int n8) {
  int i = blockIdx.x * 256 + threadIdx.x;
  if (i >= n8) return;
  *reinterpret_cast<v8s*>(out + (size_t)i * 8) = ld8(in + (size_t)i * 8);
}

// merged convert: x (4096 blocks) + Wq (2048) + Wk (2048) in one launch
__global__ __launch_bounds__(256) void cvt3_f32_bf16(const float* __restrict__ a, bf16* __restrict__ oa,
                                                     const float* __restrict__ b, bf16* __restrict__ ob,
                                                     const float* __restrict__ c, bf16* __restrict__ oc) {
  const int bx = blockIdx.x;
  if (bx < 4096) {
    size_t i = (size_t)bx * 256 + threadIdx.x;
    *reinterpret_cast<v8s*>(oa + i * 8) = ld8(a + i * 8);
  } else if (bx < 6144) {
    size_t i = (size_t)(bx - 4096) * 256 + threadIdx.x;
    *reinterpret_cast<v8s*>(ob + i * 8) = ld8(b + i * 8);
  } else {
    size_t i = (size_t)(bx - 6144) * 256 + threadIdx.x;
    *reinterpret_cast<v8s*>(oc + i * 8) = ld8(c + i * 8);
  }
}

// ===========================================================================
// QK GEMM, 256x256 tile, 8-phase counted-vmcnt schedule (m201 template port).
// A [4096,2048] bf16, W=[Wq;Wk] [4096,2048] bf16. Grid 16x16 = 256 blocks
// (exactly 1/CU). 512 threads = 8 waves as 2(M) x 4(N); per-wave C 128x64.
// LDS 128 KiB: buf0 (even K-tiles) + buf1 (odd), each A[256][64]+B[256][64].
// Swizzle: storage 16B-block c holds global block c^(row&7) (pre-swizzled
// global source; reads XOR the same) - rule 21 both-sides involution.
// Schedule per iteration j (K-tiles 2j, 2j+1), phases p=0..7:
//   p<4: read buf0 quadrant (2 frag-rows), stage pair p of tile 2j+1 -> buf1
//   p>=4: read buf1 quadrant,              stage pair p-4 of tile 2j+2 -> buf0
//   p==0/4: stage pair first, then s_waitcnt vmcnt(2) (= the 8 loads of the
//   tile about to be read are landed; the 2 just-issued stay in flight),
//   raw s_barrier (no implicit drain), sched_barrier pin. vmcnt(0) only at
//   the last iteration's p==4. End of every phase: raw s_barrier.
// Hazards: buf freed at p3/p7 (reads consumed by MFMA via compiler lgkmcnt
// before the end barrier) before the opposite half stages into it.
// ===========================================================================
template <int PR>
__device__ __forceinline__ void stage_pair(const bf16* Arow, const bf16* Wrow,
                                           int ktile, bf16* AsD, bf16* BsD,
                                           int tid, int wave) {
  const int k0 = ktile * 64;
#pragma unroll
  for (int u = 0; u < 2; ++u) {
    const int i = PR * 2 + u;            // 0..7 (compile-time)
    const int blk = i * 512 + tid;       // 0..4095
    if (i < 4) {                         // A half-tiles: rows 0-127, 128-255
      const int row = blk >> 3, c = blk & 7;
      gll16(Arow + (size_t)row * D_ + k0 + ((c ^ (row & 7)) << 3),
            AsD + (i * 512 + wave * 64) * 8);
    } else {                             // B half-tiles
      const int bb = blk - 2048;
      const int row = bb >> 3, c = bb & 7;
      gll16(Wrow + (size_t)row * D_ + k0 + ((c ^ (row & 7)) << 3),
            BsD + ((i - 4) * 512 + wave * 64) * 8);
    }
  }
}

__global__ __launch_bounds__(512, 2) void gemm_qk8(const bf16* __restrict__ A,
                                                   const bf16* __restrict__ W,
                                                   const float* __restrict__ bias0,
                                                   const float* __restrict__ bias1,
                                                   bf16* __restrict__ out0,
                                                   bf16* __restrict__ out1) {
  __shared__ __align__(16) bf16 As0[256 * 64];
  __shared__ __align__(16) bf16 Bs0[256 * 64];
  __shared__ __align__(16) bf16 As1[256 * 64];
  __shared__ __align__(16) bf16 Bs1[256 * 64];
  const int tid  = threadIdx.x;
  const int lane = tid & 63, wave = tid >> 6;
  const int wm = wave >> 2, wn = wave & 3;      // 2M x 4N
  const int quad = lane >> 4, l16 = lane & 15;
  const int swz  = l16 & 7;
  const int bm = blockIdx.y * 256, bn = blockIdx.x * 256;
  const bf16* Arow = A + (size_t)bm * D_;
  const bf16* Wrow = W + (size_t)bn * D_;

  v4f acc[8][4] = {};

  // prologue: tile 0 -> buf0 (8 loads/wave)
  stage_pair<0>(Arow, Wrow, 0, As0, Bs0, tid, wave);
  stage_pair<1>(Arow, Wrow, 0, As0, Bs0, tid, wave);
  stage_pair<2>(Arow, Wrow, 0, As0, Bs0, tid, wave);
  stage_pair<3>(Arow, Wrow, 0, As0, Bs0, tid, wave);

  constexpr int NITER = (D_ / 64) / 2;   // 16 iterations, 2 K-tiles each
  for (int j = 0; j < NITER; ++j) {
    const bool notlast = (j + 1 < NITER);
#pragma unroll
    for (int p = 0; p < 8; ++p) {
      const bf16* Ard = (p < 4) ? As0 : As1;   // compile-time under unroll
      const bf16* Brd = (p < 4) ? Bs0 : Bs1;
      bf16* AsD = (p < 4) ? As1 : As0;
      bf16* BsD = (p < 4) ? Bs1 : Bs0;
      const int tstage = (p < 4) ? (2 * j + 1) : (2 * j + 2);

      if (p == 0) {
        stage_pair<0>(Arow, Wrow, tstage, AsD, BsD, tid, wave);
        asm volatile("s_waitcnt vmcnt(2)" ::: "memory");
        __builtin_amdgcn_sched_barrier(0);
        __builtin_amdgcn_s_barrier();
        __builtin_amdgcn_sched_barrier(0);
      } else if (p == 4) {
        if (notlast) {
          stage_pair<0>(Arow, Wrow, tstage, AsD, BsD, tid, wave);
          asm volatile("s_waitcnt vmcnt(2)" ::: "memory");
        } else {
          asm volatile("s_waitcnt vmcnt(0)" ::: "memory");
        }
        __builtin_amdgcn_sched_barrier(0);
        __builtin_amdgcn_s_barrier();
        __builtin_amdgcn_sched_barrier(0);
      } else if (p < 4) {
        if (p == 1) stage_pair<1>(Arow, Wrow, tstage, AsD, BsD, tid, wave);
        if (p == 2) stage_pair<2>(Arow, Wrow, tstage, AsD, BsD, tid, wave);
        if (p == 3) stage_pair<3>(Arow, Wrow, tstage, AsD, BsD, tid, wave);
      } else {
        if (notlast) {
          if (p == 5) stage_pair<1>(Arow, Wrow, tstage, AsD, BsD, tid, wave);
          if (p == 6) stage_pair<2>(Arow, Wrow, tstage, AsD, BsD, tid, wave);
          if (p == 7) stage_pair<3>(Arow, Wrow, tstage, AsD, BsD, tid, wave);
        }
      }

      // ds-load register subtile: 4 A-frags (2 frag-rows x 2 ksteps) + 8 B
      const int pp = p & 3;
      v8s af[2][2], bfr[4][2];
#pragma unroll
      for (int mi = 0; mi < 2; ++mi)
#pragma unroll
        for (int kk = 0; kk < 2; ++kk) {
          const int row = wm * 128 + (pp * 2 + mi) * 16 + l16;
          af[mi][kk] = *reinterpret_cast<const v8s*>(
              &Ard[row * 64 + (((kk * 4 + quad) ^ swz) << 3)]);
        }
#pragma unroll
      for (int ni = 0; ni < 4; ++ni)
#pragma unroll
        for (int kk = 0; kk < 2; ++kk) {
          const int row = wn * 64 + ni * 16 + l16;
          bfr[ni][kk] = *reinterpret_cast<const v8s*>(
              &Brd[row * 64 + (((kk * 4 + quad) ^ swz) << 3)]);
        }
      __builtin_amdgcn_s_setprio(1);
#pragma unroll
      for (int kk = 0; kk < 2; ++kk)
#pragma unroll
        for (int mi = 0; mi < 2; ++mi)
#pragma unroll
          for (int ni = 0; ni < 4; ++ni)
            acc[pp * 2 + mi][ni] = __builtin_amdgcn_mfma_f32_16x16x32_bf16(
                af[mi][kk], bfr[ni][kk], acc[pp * 2 + mi][ni], 0, 0, 0);
      __builtin_amdgcn_s_setprio(0);
      __builtin_amdgcn_s_barrier();
      __builtin_amdgcn_sched_barrier(0);
    }
  }

  // epilogue: C-write (Q scaled / K), same mapping as gemm_bt MODE 0
  constexpr float QSCALE = 0.12752003912f;  // 1/sqrt(128) * log2(e)
  const int proj = bn >> 11;                 // block-uniform: 0=Q, 1=K
  const float* bias = proj ? bias1 : bias0;
  bf16* outp = proj ? out1 : out0;
  const int bnl = bn & 2047;
#pragma unroll
  for (int ni = 0; ni < 4; ++ni) {
    const int nl = bnl + wn * 64 + ni * 16 + l16;
    const float bv = bias[nl];
    const int hh = nl >> 7, d = nl & (DH_ - 1);
#pragma unroll
    for (int mi = 0; mi < 8; ++mi) {
      const int m0 = bm + wm * 128 + mi * 16 + quad * 4;
#pragma unroll
      for (int r = 0; r < 4; ++r) {
        const int m = m0 + r;
        float v = acc[mi][ni][r] + bv;
        if (!proj) v *= QSCALE;
        const int bb = m >> 11, s = m & (S_ - 1);
        outp[((size_t)(bb * H_ + hh) * S_ + s) * DH_ + d] = __float2bfloat16(v);
      }
    }
  }
}

// C = A @ W^T + bias ; A [M,K] bf16 row-major, W [N,K] bf16 row-major.
// 128x128 tile, BK=64, single-buffered LDS (32 KiB), global_load_lds
// width-16 staging with both-sides XOR swizzle. (~490 TF/unit proven.)
// MODE 2: V -> [B,H,dh,S]  (transposed for PV fragment loads)
// MODE 3: plain [M,N] f32 out (final projection)
template <int MODE, typename TOUT>
__global__ __launch_bounds__(256) void gemm_bt(const bf16* __restrict__ A,
                                               const bf16* __restrict__ W,
                                               const float* __restrict__ bias0,
                                               TOUT* __restrict__ out0) {
  __shared__ __align__(16) bf16 As[128 * 64];
  __shared__ __align__(16) bf16 Bs[128 * 64];
  const int tid  = threadIdx.x;
  const int lane = tid & 63, wave = tid >> 6;
  const int wm = wave >> 1, wn = wave & 1;
  const int quad = lane >> 4, l16 = lane & 15;
  const int swz  = l16 & 7;
  const int bm = blockIdx.y * 128, bn = blockIdx.x * 128;

  const bf16* Arow = A + (size_t)bm * D_;
  const bf16* Wrow = W + (size_t)bn * D_;

  v4f acc[4][4] = {};
  for (int k0 = 0; k0 < D_; k0 += 64) {
#pragma unroll
    for (int j = 0; j < 4; ++j) {
      const int blk = j * 256 + tid;
      const int row = blk >> 3, c = blk & 7;
      const int gcol = k0 + (((c ^ (row & 7)) << 3));
      gll16(Arow + (size_t)row * D_ + gcol, As + j * 2048 + wave * 512);
      gll16(Wrow + (size_t)row * D_ + gcol, Bs + j * 2048 + wave * 512);
    }
    __syncthreads();
    v8s af[4][2], bfr[4][2];
#pragma unroll
    for (int mi = 0; mi < 4; ++mi)
#pragma unroll
      for (int kk = 0; kk < 2; ++kk)
        af[mi][kk] = *reinterpret_cast<const v8s*>(
            &As[(wm * 64 + mi * 16 + l16) * 64 + (((kk * 4 + quad) ^ swz) << 3)]);
#pragma unroll
    for (int ni = 0; ni < 4; ++ni)
#pragma unroll
      for (int kk = 0; kk < 2; ++kk)
        bfr[ni][kk] = *reinterpret_cast<const v8s*>(
            &Bs[(wn * 64 + ni * 16 + l16) * 64 + (((kk * 4 + quad) ^ swz) << 3)]);
#pragma unroll
    for (int kk = 0; kk < 2; ++kk)
#pragma unroll
      for (int mi = 0; mi < 4; ++mi)
#pragma unroll
        for (int ni = 0; ni < 4; ++ni)
          acc[mi][ni] = __builtin_amdgcn_mfma_f32_16x16x32_bf16(
              af[mi][kk], bfr[ni][kk], acc[mi][ni], 0, 0, 0);
    __syncthreads();
  }

#pragma unroll
  for (int ni = 0; ni < 4; ++ni) {
    const int nl = bn + wn * 64 + ni * 16 + l16;
    const float bv = bias0[nl];
#pragma unroll
    for (int mi = 0; mi < 4; ++mi) {
      const int m0 = bm + wm * 64 + mi * 16 + quad * 4;
#pragma unroll
      for (int r = 0; r < 4; ++r) {
        const int m = m0 + r;
        float v = acc[mi][ni][r] + bv;
        size_t idx;
        if (MODE == 2) {
          int b = m >> 11, s = m & (S_ - 1);
          int h = nl >> 7, d = nl & (DH_ - 1);
          idx = ((size_t)(b * H_ + h) * DH_ + d) * S_ + s;
        } else {
          idx = (size_t)m * D_ + nl;
        }
        store_out(out0 + idx, v);
      }
    }
  }
}

// Flash attention, causal. Q/K: [B,H,S,dh], Vt: [B,H,dh,S] (all bf16). Out: [B,S,D] bf16.
// Block = 128 Q rows (8 waves x 16 rows), K-tile = 64 keys, 512 threads.
// Round-7 verified (112 us): 50 KB LDS -> 3 blocks/CU TLP; qt-flip pairing.
#define QBLK 128
__global__ __launch_bounds__(512, 4) void attn_fused(const bf16* __restrict__ Q,
                                                     const bf16* __restrict__ K,
                                                     const bf16* __restrict__ Vt,
                                                     bf16* __restrict__ Oa) {
  __shared__ __align__(16) bf16 Ks[64 * 128];   // [key][d] linear; blk c holds global c^(key&7)
  __shared__ __align__(16) bf16 Vs[128 * 64];   // [d][key] linear; blk c holds global c^(d&7)
  __shared__ __align__(16) bf16 Ps[8][16 * 72]; // per-wave P, padded stride 72
  const int tid  = threadIdx.x;
  const int lane = tid & 63, wave = tid >> 6;
  const int quad = lane >> 4, l16 = lane & 15;
  const int swz  = l16 & 7;
  const int qtd = (int)gridDim.x - 1 - (int)blockIdx.x;   // descending
  const int qt  = (blockIdx.y & 16) ? (int)blockIdx.x : qtd;
  const int bh = blockIdx.y;
  const int b = bh >> 4, h = bh & 15;
  const bf16* Qh = Q  + (size_t)bh * S_ * DH_;
  const bf16* Kh = K  + (size_t)bh * S_ * DH_;
  const bf16* Vh = Vt + (size_t)bh * DH_ * S_;

  const int qrow0 = qt * QBLK + wave * 16;
  v8s qf[4];
#pragma unroll
  for (int kk = 0; kk < 4; ++kk)
    qf[kk] = *reinterpret_cast<const v8s*>(&Qh[(size_t)(qrow0 + l16) * DH_ + kk * 32 + quad * 8]);

  v4f acc_o[8] = {};
  float m_i[4], l_i[4];
#pragma unroll
  for (int r = 0; r < 4; ++r) { m_i[r] = -1.0e30f; l_i[r] = 0.f; }

  const int nkt = 2 * qt + 2;
  for (int kt = 0; kt < nkt; ++kt) {
    const int kbase = kt * 64;
#pragma unroll
    for (int rr = 0; rr < 2; ++rr) {
      const int g = rr * 512 + tid;
      const int krow = g >> 4, kc = g & 15;           // K: 16 x 16B blocks/row
      gll16(Kh + (size_t)(kbase + krow) * DH_ + ((kc ^ (krow & 7)) << 3),
            Ks + rr * 4096 + wave * 512);
      const int vrow = g >> 3, vc = g & 7;            // V: 8 x 16B blocks/row
      gll16(Vh + (size_t)vrow * S_ + kbase + ((vc ^ (vrow & 7)) << 3),
            Vs + rr * 4096 + wave * 512);
    }
    __syncthreads();   // drains vmcnt (gll16) + all waves staged

    const bool active = (kbase <= qrow0 + 15);
    if (active) {
      v4f sc[4];
      __builtin_amdgcn_s_setprio(1);
#pragma unroll
      for (int nt = 0; nt < 4; ++nt) {
        v4f a = {};
#pragma unroll
        for (int kk = 0; kk < 4; ++kk) {
          v8s kf = *reinterpret_cast<const v8s*>(
              &Ks[(nt * 16 + l16) * 128 + (((kk * 4 + quad) ^ swz) << 3)]);
          a = __builtin_amdgcn_mfma_f32_16x16x32_bf16(qf[kk], kf, a, 0, 0, 0);
        }
        sc[nt] = a;
      }
      __builtin_amdgcn_s_setprio(0);
      if (kbase + 63 > qrow0) {   // diagonal tile: causal mask
#pragma unroll
        for (int nt = 0; nt < 4; ++nt)
#pragma unroll
          for (int r = 0; r < 4; ++r) {
            int kc2 = kbase + nt * 16 + l16;
            int qr = qrow0 + quad * 4 + r;
            if (kc2 > qr) sc[nt][r] = -1.0e30f;
          }
      }
#pragma unroll
      for (int r = 0; r < 4; ++r) {
        float mx = fmaxf(fmaxf(sc[0][r], sc[1][r]), fmaxf(sc[2][r], sc[3][r]));
        mx = fmaxf(mx, __shfl_xor(mx, 1));
        mx = fmaxf(mx, __shfl_xor(mx, 2));
        mx = fmaxf(mx, __shfl_xor(mx, 4));
        mx = fmaxf(mx, __shfl_xor(mx, 8));
        if (mx > m_i[r] + 8.0f) {   // T13 defer-max
          float alpha = exp2f(m_i[r] - mx);
          m_i[r] = mx;
          l_i[r] *= alpha;
#pragma unroll
          for (int nt8 = 0; nt8 < 8; ++nt8) acc_o[nt8][r] *= alpha;
        }
        const float mm = m_i[r];
        float s0 = exp2f(sc[0][r] - mm);
        float s1 = exp2f(sc[1][r] - mm);
        float s2 = exp2f(sc[2][r] - mm);
        float s3 = exp2f(sc[3][r] - mm);
        sc[0][r] = s0; sc[1][r] = s1; sc[2][r] = s2; sc[3][r] = s3;
        float t = s0 + s1 + s2 + s3;
        t += __shfl_xor(t, 1); t += __shfl_xor(t, 2);
        t += __shfl_xor(t, 4); t += __shfl_xor(t, 8);
        l_i[r] += t;
      }
#pragma unroll
      for (int nt = 0; nt < 4; ++nt)
#pragma unroll
        for (int r = 0; r < 4; ++r)
          Ps[wave][(quad * 4 + r) * 72 + nt * 16 + l16] = __float2bfloat16(sc[nt][r]);
      asm volatile("s_waitcnt lgkmcnt(0)" ::: "memory");
      __builtin_amdgcn_s_setprio(1);
#pragma unroll
      for (int kk2 = 0; kk2 < 2; ++kk2) {
        v8s pf = *reinterpret_cast<const v8s*>(&Ps[wave][l16 * 72 + kk2 * 32 + quad * 8]);
#pragma unroll
        for (int nt8 = 0; nt8 < 8; ++nt8) {
          v8s vf = *reinterpret_cast<const v8s*>(
              &Vs[(nt8 * 16 + l16) * 64 + (((kk2 * 4 + quad) ^ swz) << 3)]);
          acc_o[nt8] = __builtin_amdgcn_mfma_f32_16x16x32_bf16(pf, vf, acc_o[nt8], 0, 0, 0);
        }
      }
      __builtin_amdgcn_s_setprio(0);
    }
    __syncthreads();
  }

#pragma unroll
  for (int r = 0; r < 4; ++r) {
    const float inv = 1.0f / l_i[r];
    const int srow = qrow0 + quad * 4 + r;
#pragma unroll
    for (int nt8 = 0; nt8 < 8; ++nt8)
      Oa[((size_t)b * S_ + srow) * D_ + h * DH_ + nt8 * 16 + l16] =
          __float2bfloat16(acc_o[nt8][r] * inv);
  }
}

extern "C" void kernel_launch(void* const* d_in, const int* in_sizes, int n_in,
                              void* d_out, int out_size, void* d_ws, size_t ws_size,
                              hipStream_t stream) {
  // Canary: all-zero output (absmax exactly 3.5625) signals a tripped assumption.
  if (n_in != 9 ||
      in_sizes[0] != M_ * D_ ||
      in_sizes[1] != D_ * D_ || in_sizes[2] != D_ ||
      in_sizes[3] != D_ * D_ || in_sizes[4] != D_ ||
      in_sizes[5] != D_ * D_ || in_sizes[6] != D_ ||
      in_sizes[7] != D_ * D_ || in_sizes[8] != D_ ||
      out_size != M_ * D_)
    return;

  const float* x  = (const float*)d_in[0];
  const float* Wq = (const float*)d_in[1];
  const float* bq = (const float*)d_in[2];
  const float* Wk = (const float*)d_in[3];
  const float* bk = (const float*)d_in[4];
  const float* Wv = (const float*)d_in[5];
  const float* bv = (const float*)d_in[6];
  const float* Wo = (const float*)d_in[7];
  const float* bo = (const float*)d_in[8];
  float* out = (float*)d_out;   // OUTPUT IS FLOAT32 (reference output dtype)

  const size_t NT = (size_t)M_ * D_;   // 8388608 elems per tensor
  const size_t WN = (size_t)D_ * D_;   // 4194304 elems per weight
  // Buffer plan:
  //   d_out (33.6 MB f32):  [0,16.8) qws (bf16 Q), [16.8,33.6) x_bf16
  //     both dead before the final GEMM overwrites d_out.
  //   ws (50.3 MB): kws | vtw | aws
  //     Wq||Wk concat (16.8 MB) fills aws before the QK GEMM; Wv reuses
  //     aws[0:8.4) before the V GEMM; aws becomes the attn output after
  //     (weights dead); Wo parks in kws (K dead after attn).
  bf16* qws   = (bf16*)d_out;
  bf16* xbf   = (bf16*)d_out + NT;
  bf16* kws   = (bf16*)d_ws;
  bf16* vtw   = kws + NT;
  bf16* aws   = vtw + NT;
  bf16* wqk   = aws;            // [4096][2048] bf16 concat
  bf16* wv_s  = aws;            // [2048][2048]
  bf16* wo_s  = kws;            // [2048][2048] (post-attn)

  const int N8W = D_ * D_ / 8;   // 524288

  dim3 bb(256);
  // x + Wq + Wk in one merged convert launch (4096 + 2048 + 2048 blocks)
  cvt3_f32_bf16<<<8192, bb, 0, stream>>>(x, xbf, Wq, wqk, Wk, wqk + WN);

  // QK fused: 256^2 8-phase, grid 16x16 = 256 blocks (1/CU)
  gemm_qk8<<<dim3(16, 16), dim3(512), 0, stream>>>(xbf, wqk, bq, bk, qws, kws);

  cvt_f32_bf16<<<N8W / 256, bb, 0, stream>>>(Wv, wv_s, N8W);
  gemm_bt<2, bf16><<<dim3(16, 32), bb, 0, stream>>>(xbf, wv_s, bv, vtw);

  attn_fused<<<dim3(S_ / QBLK, B_ * H_), dim3(512), 0, stream>>>(qws, kws, vtw, aws);

  cvt_f32_bf16<<<N8W / 256, bb, 0, stream>>>(Wo, wo_s, N8W);
  gemm_bt<3, float><<<dim3(16, 32), bb, 0, stream>>>(aws, wo_s, bo, out);
}

// Round 10
// 401.436 us; speedup vs baseline: 1.1847x; 1.0141x over previous
//
#include <hip/hip_runtime.h>
#include <hip/hip_bf16.h>

#define B_  2
#define S_  2048
#define D_  2048
#define H_  16
#define DH_ 128
#define M_  (B_*S_)   // 4096

typedef __hip_bfloat16 bf16;
typedef float v4f __attribute__((ext_vector_type(4)));
typedef short v8s __attribute__((ext_vector_type(8)));

__device__ __forceinline__ short f2s(float x) {
  bf16 h = __float2bfloat16(x);
  return *reinterpret_cast<const short*>(&h);
}
// load 8 contiguous f32 elems, convert to bf16 bits
__device__ __forceinline__ v8s ld8(const float* p) {
  v4f a = *reinterpret_cast<const v4f*>(p);
  v4f b = *reinterpret_cast<const v4f*>(p + 4);
  v8s r = { f2s(a[0]), f2s(a[1]), f2s(a[2]), f2s(a[3]),
            f2s(b[0]), f2s(b[1]), f2s(b[2]), f2s(b[3]) };
  return r;
}
__device__ __forceinline__ void store_out(bf16* p, float v)  { *p = __float2bfloat16(v); }
__device__ __forceinline__ void store_out(float* p, float v) { *p = v; }

// async 16B global->LDS (direct, no VGPR round-trip). LDS dest is
// wave-uniform base + lane*16; global src is per-lane.
__device__ __forceinline__ void gll16(const bf16* g, bf16* l) {
  __builtin_amdgcn_global_load_lds((const __attribute__((address_space(1))) void*)g,
                                   (__attribute__((address_space(3))) void*)l,
                                   16, 0, 0);
}

// streaming f32 -> bf16 convert, 8 elems/thread
__global__ __launch_bounds__(256) void cvt_f32_bf16(const float* __restrict__ in,
                                                    bf16* __restrict__ out, int n8) {
  int i = blockIdx.x * 256 + threadIdx.x;
  if (i >= n8) return;
  *reinterpret_cast<v8s*>(out + (size_t)i * 8) = ld8(in + (size_t)i * 8);
}

// merged convert: x (4096 blocks) + Wq (2048) + Wk (2048) in one launch
__global__ __launch_bounds__(256) void cvt3_f32_bf16(const float* __restrict__ a, bf16* __restrict__ oa,
                                                     const float* __restrict__ b, bf16* __restrict__ ob,
                                                     const float* __restrict__ c, bf16* __restrict__ oc) {
  const int bx = blockIdx.x;
  if (bx < 4096) {
    size_t i = (size_t)bx * 256 + threadIdx.x;
    *reinterpret_cast<v8s*>(oa + i * 8) = ld8(a + i * 8);
  } else if (bx < 6144) {
    size_t i = (size_t)(bx - 4096) * 256 + threadIdx.x;
    *reinterpret_cast<v8s*>(ob + i * 8) = ld8(b + i * 8);
  } else {
    size_t i = (size_t)(bx - 6144) * 256 + threadIdx.x;
    *reinterpret_cast<v8s*>(oc + i * 8) = ld8(c + i * 8);
  }
}

// ===========================================================================
// QK GEMM, 256x256 tile, pipelined counted-vmcnt schedule.
// Grid 16x16 = 256 blocks (1/CU), 512 thr = 8 waves (2M x 4N), per-wave C
// 128x64 = acc[8][4]. LDS 128 KiB double buffer.
// Per K-tile t (buf = t&1): B frags read ONCE (8 ds_read); A frags in two
// alternating sets of 4, read one phase ahead (compiler emits counted
// lgkmcnt); stage pairs 1-3 of tile t+1 spread over phases 0-2; boundary:
//   sched_barrier -> s_barrier (readers done) -> sched_barrier ->
//   stage pair0 of tile t+2 into the just-freed buffer -> vmcnt(2)
//   (tile t+1's 8 loads landed; 2 newest stay in flight) ->
//   sched_barrier -> s_barrier (visibility) -> sched_barrier.
// The sched_barrier(0) pins are REQUIRED: llvm s_barrier is not a compiler
// memory fence, so without pins the scheduler can migrate gll16 LDS-writes
// across the barrier into a buffer other waves still read (rule 18 family;
// the r8 build that ran used exactly this discipline).
// Swizzle: storage 16B-block c holds global block c^(row&7) (both sides).
// ===========================================================================
template <int PR>
__device__ __forceinline__ void stage_pair(const bf16* Arow, const bf16* Wrow,
                                           int ktile, bf16* AsD, bf16* BsD,
                                           int tid, int wave) {
  const int k0 = ktile * 64;
#pragma unroll
  for (int u = 0; u < 2; ++u) {
    const int i = PR * 2 + u;            // 0..7 (compile-time)
    const int blk = i * 512 + tid;       // 0..4095
    if (i < 4) {                         // A half-tiles: rows 0-255
      const int row = blk >> 3, c = blk & 7;
      gll16(Arow + (size_t)row * D_ + k0 + ((c ^ (row & 7)) << 3),
            AsD + (i * 512 + wave * 64) * 8);
    } else {                             // B half-tiles
      const int bb = blk - 2048;
      const int row = bb >> 3, c = bb & 7;
      gll16(Wrow + (size_t)row * D_ + k0 + ((c ^ (row & 7)) << 3),
            BsD + ((i - 4) * 512 + wave * 64) * 8);
    }
  }
}

#define RD_A(dst, PP)                                                         \
  _Pragma("unroll")                                                           \
  for (int mi = 0; mi < 2; ++mi)                                              \
    _Pragma("unroll")                                                         \
    for (int kk = 0; kk < 2; ++kk)                                            \
      dst[mi][kk] = *reinterpret_cast<const v8s*>(                            \
          &Ard[(wm * 128 + ((PP) * 2 + mi) * 16 + l16) * 64 +                 \
               (((kk * 4 + quad) ^ swz) << 3)]);

#define MFMA_Q(af, Q)                                                         \
  __builtin_amdgcn_s_setprio(1);                                              \
  _Pragma("unroll")                                                           \
  for (int kk = 0; kk < 2; ++kk)                                              \
    _Pragma("unroll")                                                         \
    for (int mi = 0; mi < 2; ++mi)                                            \
      _Pragma("unroll")                                                       \
      for (int ni = 0; ni < 4; ++ni)                                          \
        acc[(Q) * 2 + mi][ni] = __builtin_amdgcn_mfma_f32_16x16x32_bf16(      \
            af[mi][kk], bfr[ni][kk], acc[(Q) * 2 + mi][ni], 0, 0, 0);         \
  __builtin_amdgcn_s_setprio(0);

__device__ __forceinline__ void ktile_body(
    int t, const bf16* Ard, const bf16* Brd,    // read buffers (tile t)
    bf16* AsW, bf16* BsW,                       // write buffers (tile t+1)
    bf16* AsR, bf16* BsR,                       // == Ard/Brd, boundary target (tile t+2)
    const bf16* Arow, const bf16* Wrow,
    int tid, int wave, int wm, int wn, int quad, int l16, int swz,
    v4f (&acc)[8][4]) {
  // B frags: once per K-tile (phase-invariant rows)
  v8s bfr[4][2];
#pragma unroll
  for (int ni = 0; ni < 4; ++ni)
#pragma unroll
    for (int kk = 0; kk < 2; ++kk)
      bfr[ni][kk] = *reinterpret_cast<const v8s*>(
          &Brd[(wn * 64 + ni * 16 + l16) * 64 + (((kk * 4 + quad) ^ swz) << 3)]);
  v8s afA[2][2], afB[2][2];
  RD_A(afA, 0)
  const bool st = (t + 1 < 32);
  // phase 0: stage pair1(t+1), prefetch afB(p1), MFMA q0
  if (st) stage_pair<1>(Arow, Wrow, t + 1, AsW, BsW, tid, wave);
  RD_A(afB, 1)
  MFMA_Q(afA, 0)
  // phase 1: stage pair2, prefetch afA(p2), MFMA q1
  if (st) stage_pair<2>(Arow, Wrow, t + 1, AsW, BsW, tid, wave);
  RD_A(afA, 2)
  MFMA_Q(afB, 1)
  // phase 2: stage pair3, prefetch afB(p3), MFMA q2
  if (st) stage_pair<3>(Arow, Wrow, t + 1, AsW, BsW, tid, wave);
  RD_A(afB, 3)
  MFMA_Q(afA, 2)
  // phase 3: MFMA q3
  MFMA_Q(afB, 3)
  // boundary: readers of this buffer done -> restage it; make t+1 visible
  __builtin_amdgcn_sched_barrier(0);
  __builtin_amdgcn_s_barrier();
  __builtin_amdgcn_sched_barrier(0);
  if (t + 2 < 32) {
    stage_pair<0>(Arow, Wrow, t + 2, AsR, BsR, tid, wave);
    asm volatile("s_waitcnt vmcnt(2)" ::: "memory");
  } else {
    asm volatile("s_waitcnt vmcnt(0)" ::: "memory");
  }
  __builtin_amdgcn_sched_barrier(0);
  __builtin_amdgcn_s_barrier();
  __builtin_amdgcn_sched_barrier(0);
}

__global__ __launch_bounds__(512, 2) void gemm_qk8(const bf16* __restrict__ A,
                                                   const bf16* __restrict__ W,
                                                   const float* __restrict__ bias0,
                                                   const float* __restrict__ bias1,
                                                   bf16* __restrict__ out0,
                                                   bf16* __restrict__ out1) {
  __shared__ __align__(16) bf16 As0[256 * 64];
  __shared__ __align__(16) bf16 Bs0[256 * 64];
  __shared__ __align__(16) bf16 As1[256 * 64];
  __shared__ __align__(16) bf16 Bs1[256 * 64];
  const int tid  = threadIdx.x;
  const int lane = tid & 63, wave = tid >> 6;
  const int wm = wave >> 2, wn = wave & 3;      // 2M x 4N
  const int quad = lane >> 4, l16 = lane & 15;
  const int swz  = l16 & 7;
  const int bm = blockIdx.y * 256, bn = blockIdx.x * 256;
  const bf16* Arow = A + (size_t)bm * D_;
  const bf16* Wrow = W + (size_t)bn * D_;

  v4f acc[8][4] = {};

  // prologue: tile0 -> buf0 (8 loads), pre-issue pair0 of tile1 -> buf1
  stage_pair<0>(Arow, Wrow, 0, As0, Bs0, tid, wave);
  stage_pair<1>(Arow, Wrow, 0, As0, Bs0, tid, wave);
  stage_pair<2>(Arow, Wrow, 0, As0, Bs0, tid, wave);
  stage_pair<3>(Arow, Wrow, 0, As0, Bs0, tid, wave);
  stage_pair<0>(Arow, Wrow, 1, As1, Bs1, tid, wave);
  asm volatile("s_waitcnt vmcnt(2)" ::: "memory");
  __builtin_amdgcn_sched_barrier(0);
  __builtin_amdgcn_s_barrier();
  __builtin_amdgcn_sched_barrier(0);

  for (int j = 0; j < 16; ++j) {
    ktile_body(2 * j,     As0, Bs0, As1, Bs1, As0, Bs0,
               Arow, Wrow, tid, wave, wm, wn, quad, l16, swz, acc);
    ktile_body(2 * j + 1, As1, Bs1, As0, Bs0, As1, Bs1,
               Arow, Wrow, tid, wave, wm, wn, quad, l16, swz, acc);
  }

  // epilogue: C-write (Q scaled / K)
  constexpr float QSCALE = 0.12752003912f;  // 1/sqrt(128) * log2(e)
  const int proj = bn >> 11;                 // block-uniform: 0=Q, 1=K
  const float* bias = proj ? bias1 : bias0;
  bf16* outp = proj ? out1 : out0;
  const int bnl = bn & 2047;
#pragma unroll
  for (int ni = 0; ni < 4; ++ni) {
    const int nl = bnl + wn * 64 + ni * 16 + l16;
    const float bv = bias[nl];
    const int hh = nl >> 7, d = nl & (DH_ - 1);
#pragma unroll
    for (int mi = 0; mi < 8; ++mi) {
      const int m0 = bm + wm * 128 + mi * 16 + quad * 4;
#pragma unroll
      for (int r = 0; r < 4; ++r) {
        const int m = m0 + r;
        float v = acc[mi][ni][r] + bv;
        if (!proj) v *= QSCALE;
        const int bb = m >> 11, s = m & (S_ - 1);
        outp[((size_t)(bb * H_ + hh) * S_ + s) * DH_ + d] = __float2bfloat16(v);
      }
    }
  }
}

// C = A @ W^T + bias ; A [M,K] bf16 row-major, W [N,K] bf16 row-major.
// 128x128 tile, BK=64, single-buffered LDS (32 KiB), global_load_lds
// width-16 staging with both-sides XOR swizzle. (~490 TF/unit proven.)
// MODE 2: V -> [B,H,dh,S]  (transposed for PV fragment loads)
// MODE 3: plain [M,N] f32 out (final projection)
template <int MODE, typename TOUT>
__global__ __launch_bounds__(256) void gemm_bt(const bf16* __restrict__ A,
                                               const bf16* __restrict__ W,
                                               const float* __restrict__ bias0,
                                               TOUT* __restrict__ out0) {
  __shared__ __align__(16) bf16 As[128 * 64];
  __shared__ __align__(16) bf16 Bs[128 * 64];
  const int tid  = threadIdx.x;
  const int lane = tid & 63, wave = tid >> 6;
  const int wm = wave >> 1, wn = wave & 1;
  const int quad = lane >> 4, l16 = lane & 15;
  const int swz  = l16 & 7;
  const int bm = blockIdx.y * 128, bn = blockIdx.x * 128;

  const bf16* Arow = A + (size_t)bm * D_;
  const bf16* Wrow = W + (size_t)bn * D_;

  v4f acc[4][4] = {};
  for (int k0 = 0; k0 < D_; k0 += 64) {
#pragma unroll
    for (int j = 0; j < 4; ++j) {
      const int blk = j * 256 + tid;
      const int row = blk >> 3, c = blk & 7;
      const int gcol = k0 + (((c ^ (row & 7)) << 3));
      gll16(Arow + (size_t)row * D_ + gcol, As + j * 2048 + wave * 512);
      gll16(Wrow + (size_t)row * D_ + gcol, Bs + j * 2048 + wave * 512);
    }
    __syncthreads();
    v8s af[4][2], bfr[4][2];
#pragma unroll
    for (int mi = 0; mi < 4; ++mi)
#pragma unroll
      for (int kk = 0; kk < 2; ++kk)
        af[mi][kk] = *reinterpret_cast<const v8s*>(
            &As[(wm * 64 + mi * 16 + l16) * 64 + (((kk * 4 + quad) ^ swz) << 3)]);
#pragma unroll
    for (int ni = 0; ni < 4; ++ni)
#pragma unroll
      for (int kk = 0; kk < 2; ++kk)
        bfr[ni][kk] = *reinterpret_cast<const v8s*>(
            &Bs[(wn * 64 + ni * 16 + l16) * 64 + (((kk * 4 + quad) ^ swz) << 3)]);
#pragma unroll
    for (int kk = 0; kk < 2; ++kk)
#pragma unroll
      for (int mi = 0; mi < 4; ++mi)
#pragma unroll
        for (int ni = 0; ni < 4; ++ni)
          acc[mi][ni] = __builtin_amdgcn_mfma_f32_16x16x32_bf16(
              af[mi][kk], bfr[ni][kk], acc[mi][ni], 0, 0, 0);
    __syncthreads();
  }

#pragma unroll
  for (int ni = 0; ni < 4; ++ni) {
    const int nl = bn + wn * 64 + ni * 16 + l16;
    const float bv = bias0[nl];
#pragma unroll
    for (int mi = 0; mi < 4; ++mi) {
      const int m0 = bm + wm * 64 + mi * 16 + quad * 4;
#pragma unroll
      for (int r = 0; r < 4; ++r) {
        const int m = m0 + r;
        float v = acc[mi][ni][r] + bv;
        size_t idx;
        if (MODE == 2) {
          int b = m >> 11, s = m & (S_ - 1);
          int h = nl >> 7, d = nl & (DH_ - 1);
          idx = ((size_t)(b * H_ + h) * DH_ + d) * S_ + s;
        } else {
          idx = (size_t)m * D_ + nl;
        }
        store_out(out0 + idx, v);
      }
    }
  }
}

// Flash attention, causal. Q/K: [B,H,S,dh], Vt: [B,H,dh,S] (all bf16). Out: [B,S,D] bf16.
// Block = 128 Q rows (8 waves x 16 rows), K-tile = 64 keys, 512 threads.
// Round-7 verified (112 us): 50 KB LDS -> 3 blocks/CU TLP; qt-flip pairing.
#define QBLK 128
__global__ __launch_bounds__(512, 4) void attn_fused(const bf16* __restrict__ Q,
                                                     const bf16* __restrict__ K,
                                                     const bf16* __restrict__ Vt,
                                                     bf16* __restrict__ Oa) {
  __shared__ __align__(16) bf16 Ks[64 * 128];   // [key][d] linear; blk c holds global c^(key&7)
  __shared__ __align__(16) bf16 Vs[128 * 64];   // [d][key] linear; blk c holds global c^(d&7)
  __shared__ __align__(16) bf16 Ps[8][16 * 72]; // per-wave P, padded stride 72
  const int tid  = threadIdx.x;
  const int lane = tid & 63, wave = tid >> 6;
  const int quad = lane >> 4, l16 = lane & 15;
  const int swz  = l16 & 7;
  const int qtd = (int)gridDim.x - 1 - (int)blockIdx.x;   // descending
  const int qt  = (blockIdx.y & 16) ? (int)blockIdx.x : qtd;
  const int bh = blockIdx.y;
  const int b = bh >> 4, h = bh & 15;
  const bf16* Qh = Q  + (size_t)bh * S_ * DH_;
  const bf16* Kh = K  + (size_t)bh * S_ * DH_;
  const bf16* Vh = Vt + (size_t)bh * DH_ * S_;

  const int qrow0 = qt * QBLK + wave * 16;
  v8s qf[4];
#pragma unroll
  for (int kk = 0; kk < 4; ++kk)
    qf[kk] = *reinterpret_cast<const v8s*>(&Qh[(size_t)(qrow0 + l16) * DH_ + kk * 32 + quad * 8]);

  v4f acc_o[8] = {};
  float m_i[4], l_i[4];
#pragma unroll
  for (int r = 0; r < 4; ++r) { m_i[r] = -1.0e30f; l_i[r] = 0.f; }

  const int nkt = 2 * qt + 2;
  for (int kt = 0; kt < nkt; ++kt) {
    const int kbase = kt * 64;
#pragma unroll
    for (int rr = 0; rr < 2; ++rr) {
      const int g = rr * 512 + tid;
      const int krow = g >> 4, kc = g & 15;           // K: 16 x 16B blocks/row
      gll16(Kh + (size_t)(kbase + krow) * DH_ + ((kc ^ (krow & 7)) << 3),
            Ks + rr * 4096 + wave * 512);
      const int vrow = g >> 3, vc = g & 7;            // V: 8 x 16B blocks/row
      gll16(Vh + (size_t)vrow * S_ + kbase + ((vc ^ (vrow & 7)) << 3),
            Vs + rr * 4096 + wave * 512);
    }
    __syncthreads();   // drains vmcnt (gll16) + all waves staged

    const bool active = (kbase <= qrow0 + 15);
    if (active) {
      v4f sc[4];
      __builtin_amdgcn_s_setprio(1);
#pragma unroll
      for (int nt = 0; nt < 4; ++nt) {
        v4f a = {};
#pragma unroll
        for (int kk = 0; kk < 4; ++kk) {
          v8s kf = *reinterpret_cast<const v8s*>(
              &Ks[(nt * 16 + l16) * 128 + (((kk * 4 + quad) ^ swz) << 3)]);
          a = __builtin_amdgcn_mfma_f32_16x16x32_bf16(qf[kk], kf, a, 0, 0, 0);
        }
        sc[nt] = a;
      }
      __builtin_amdgcn_s_setprio(0);
      if (kbase + 63 > qrow0) {   // diagonal tile: causal mask
#pragma unroll
        for (int nt = 0; nt < 4; ++nt)
#pragma unroll
          for (int r = 0; r < 4; ++r) {
            int kc2 = kbase + nt * 16 + l16;
            int qr = qrow0 + quad * 4 + r;
            if (kc2 > qr) sc[nt][r] = -1.0e30f;
          }
      }
#pragma unroll
      for (int r = 0; r < 4; ++r) {
        float mx = fmaxf(fmaxf(sc[0][r], sc[1][r]), fmaxf(sc[2][r], sc[3][r]));
        mx = fmaxf(mx, __shfl_xor(mx, 1));
        mx = fmaxf(mx, __shfl_xor(mx, 2));
        mx = fmaxf(mx, __shfl_xor(mx, 4));
        mx = fmaxf(mx, __shfl_xor(mx, 8));
        if (mx > m_i[r] + 8.0f) {   // T13 defer-max
          float alpha = exp2f(m_i[r] - mx);
          m_i[r] = mx;
          l_i[r] *= alpha;
#pragma unroll
          for (int nt8 = 0; nt8 < 8; ++nt8) acc_o[nt8][r] *= alpha;
        }
        const float mm = m_i[r];
        float s0 = exp2f(sc[0][r] - mm);
        float s1 = exp2f(sc[1][r] - mm);
        float s2 = exp2f(sc[2][r] - mm);
        float s3 = exp2f(sc[3][r] - mm);
        sc[0][r] = s0; sc[1][r] = s1; sc[2][r] = s2; sc[3][r] = s3;
        float t = s0 + s1 + s2 + s3;
        t += __shfl_xor(t, 1); t += __shfl_xor(t, 2);
        t += __shfl_xor(t, 4); t += __shfl_xor(t, 8);
        l_i[r] += t;
      }
#pragma unroll
      for (int nt = 0; nt < 4; ++nt)
#pragma unroll
        for (int r = 0; r < 4; ++r)
          Ps[wave][(quad * 4 + r) * 72 + nt * 16 + l16] = __float2bfloat16(sc[nt][r]);
      asm volatile("s_waitcnt lgkmcnt(0)" ::: "memory");
      __builtin_amdgcn_s_setprio(1);
#pragma unroll
      for (int kk2 = 0; kk2 < 2; ++kk2) {
        v8s pf = *reinterpret_cast<const v8s*>(&Ps[wave][l16 * 72 + kk2 * 32 + quad * 8]);
#pragma unroll
        for (int nt8 = 0; nt8 < 8; ++nt8) {
          v8s vf = *reinterpret_cast<const v8s*>(
              &Vs[(nt8 * 16 + l16) * 64 + (((kk2 * 4 + quad) ^ swz) << 3)]);
          acc_o[nt8] = __builtin_amdgcn_mfma_f32_16x16x32_bf16(pf, vf, acc_o[nt8], 0, 0, 0);
        }
      }
      __builtin_amdgcn_s_setprio(0);
    }
    __syncthreads();
  }

#pragma unroll
  for (int r = 0; r < 4; ++r) {
    const float inv = 1.0f / l_i[r];
    const int srow = qrow0 + quad * 4 + r;
#pragma unroll
    for (int nt8 = 0; nt8 < 8; ++nt8)
      Oa[((size_t)b * S_ + srow) * D_ + h * DH_ + nt8 * 16 + l16] =
          __float2bfloat16(acc_o[nt8][r] * inv);
  }
}

extern "C" void kernel_launch(void* const* d_in, const int* in_sizes, int n_in,
                              void* d_out, int out_size, void* d_ws, size_t ws_size,
                              hipStream_t stream) {
  // Canary: all-zero output (absmax exactly 3.5625) signals a tripped assumption.
  if (n_in != 9 ||
      in_sizes[0] != M_ * D_ ||
      in_sizes[1] != D_ * D_ || in_sizes[2] != D_ ||
      in_sizes[3] != D_ * D_ || in_sizes[4] != D_ ||
      in_sizes[5] != D_ * D_ || in_sizes[6] != D_ ||
      in_sizes[7] != D_ * D_ || in_sizes[8] != D_ ||
      out_size != M_ * D_)
    return;

  const float* x  = (const float*)d_in[0];
  const float* Wq = (const float*)d_in[1];
  const float* bq = (const float*)d_in[2];
  const float* Wk = (const float*)d_in[3];
  const float* bk = (const float*)d_in[4];
  const float* Wv = (const float*)d_in[5];
  const float* bv = (const float*)d_in[6];
  const float* Wo = (const float*)d_in[7];
  const float* bo = (const float*)d_in[8];
  float* out = (float*)d_out;   // OUTPUT IS FLOAT32 (reference output dtype)

  const size_t NT = (size_t)M_ * D_;   // 8388608 elems per tensor
  const size_t WN = (size_t)D_ * D_;   // 4194304 elems per weight
  // Buffer plan:
  //   d_out (33.6 MB f32):  [0,16.8) qws (bf16 Q), [16.8,33.6) x_bf16
  //     both dead before the final GEMM overwrites d_out.
  //   ws (50.3 MB): kws | vtw | aws
  //     Wq||Wk concat (16.8 MB) fills aws before the QK GEMM; Wv reuses
  //     aws[0:8.4) before the V GEMM; aws becomes the attn output after
  //     (weights dead); Wo parks in kws (K dead after attn).
  bf16* qws   = (bf16*)d_out;
  bf16* xbf   = (bf16*)d_out + NT;
  bf16* kws   = (bf16*)d_ws;
  bf16* vtw   = kws + NT;
  bf16* aws   = vtw + NT;
  bf16* wqk   = aws;            // [4096][2048] bf16 concat
  bf16* wv_s  = aws;            // [2048][2048]
  bf16* wo_s  = kws;            // [2048][2048] (post-attn)

  const int N8W = D_ * D_ / 8;   // 524288

  dim3 bb(256);
  // x + Wq + Wk in one merged convert launch (4096 + 2048 + 2048 blocks)
  cvt3_f32_bf16<<<8192, bb, 0, stream>>>(x, xbf, Wq, wqk, Wk, wqk + WN);

  // QK fused: 256^2 pipelined, grid 16x16 = 256 blocks (1/CU)
  gemm_qk8<<<dim3(16, 16), dim3(512), 0, stream>>>(xbf, wqk, bq, bk, qws, kws);

  cvt_f32_bf16<<<N8W / 256, bb, 0, stream>>>(Wv, wv_s, N8W);
  gemm_bt<2, bf16><<<dim3(16, 32), bb, 0, stream>>>(xbf, wv_s, bv, vtw);

  attn_fused<<<dim3(S_ / QBLK, B_ * H_), dim3(512), 0, stream>>>(qws, kws, vtw, aws);

  cvt_f32_bf16<<<N8W / 256, bb, 0, stream>>>(Wo, wo_s, N8W);
  gemm_bt<3, float><<<dim3(16, 32), bb, 0, stream>>>(aws, wo_s, bo, out);
}